// Round 1
// baseline (392.515 us; speedup 1.0000x reference)
//
#include <hip/hip_runtime.h>
#include <stdint.h>

#define THRESH 0.5f
#define PSI 0.1f

typedef short bfrag_t __attribute__((ext_vector_type(8)));     // 8 bf16 = 4 VGPRs (MFMA A/B frag)
typedef float f32x4 __attribute__((ext_vector_type(4)));       // MFMA C/D frag
typedef unsigned short u16x8 __attribute__((ext_vector_type(8)));

// async global->LDS, 16B per lane, wave-uniform LDS base + lane*16
#define GLD16(gsrc, ldst)                                                                \
    __builtin_amdgcn_global_load_lds((const __attribute__((address_space(1))) void*)(gsrc), \
                                     (__attribute__((address_space(3))) void*)(ldst),       \
                                     16, 0, 0)

__device__ __forceinline__ float dequant(float v) {
    // Branch order matches reference exactly.
    if (v > THRESH) return 1.0f;
    if (v < -THRESH) return -1.0f;
    if (fabsf(v) < PSI) return 0.0f;
    return (v + THRESH) / (2.0f * THRESH);
}

__device__ __forceinline__ unsigned short f2bf(float f) {
    // RNE float->bf16 (inputs are finite; no NaN handling needed)
    unsigned int u = __float_as_uint(f);
    u += 0x7FFFu + ((u >> 16) & 1u);
    return (unsigned short)(u >> 16);
}

__global__ void quantW_kernel(const float* __restrict__ w, unsigned short* __restrict__ wb, int n8) {
    const int stride = gridDim.x * blockDim.x;
    for (int i = blockIdx.x * blockDim.x + threadIdx.x; i < n8; i += stride) {
        const float4* p = (const float4*)w + (size_t)i * 2;
        float4 a = p[0], b = p[1];
        u16x8 o;
        o[0] = f2bf(dequant(a.x)); o[1] = f2bf(dequant(a.y));
        o[2] = f2bf(dequant(a.z)); o[3] = f2bf(dequant(a.w));
        o[4] = f2bf(dequant(b.x)); o[5] = f2bf(dequant(b.y));
        o[6] = f2bf(dequant(b.z)); o[7] = f2bf(dequant(b.w));
        *(u16x8*)(wb + (size_t)i * 8) = o;
    }
}

__global__ void cvtX_kernel(const float* __restrict__ x, unsigned short* __restrict__ xb, int n8) {
    const int stride = gridDim.x * blockDim.x;
    for (int i = blockIdx.x * blockDim.x + threadIdx.x; i < n8; i += stride) {
        const float4* p = (const float4*)x + (size_t)i * 2;
        float4 a = p[0], b = p[1];
        u16x8 o;
        o[0] = f2bf(a.x); o[1] = f2bf(a.y); o[2] = f2bf(a.z); o[3] = f2bf(a.w);
        o[4] = f2bf(b.x); o[5] = f2bf(b.y); o[6] = f2bf(b.z); o[7] = f2bf(b.w);
        *(u16x8*)(xb + (size_t)i * 8) = o;
    }
}

// ---------------------------------------------------------------------------
// Main GEMM: C[M,N] = A[M,K](bf16) * B[N,K](bf16)^T + bias, fp32 out.
// m97 structure: 128x128 tile, BK=32, 4 waves (2x2), each wave 64x64 via
// 4x4 frags of mfma_f32_16x16x32_bf16; linear LDS + global_load_lds w=16.
// ---------------------------------------------------------------------------
__global__ __launch_bounds__(256) void gemm_bt_kernel(
        const unsigned short* __restrict__ A,   // M x K, bf16 bits
        const unsigned short* __restrict__ B,   // N x K, bf16 bits
        const float* __restrict__ bias,         // N
        float* __restrict__ C,                  // M x N
        int M, int N, int K) {
    __shared__ unsigned short sA[128 * 32];
    __shared__ unsigned short sB[128 * 32];

    const int t  = threadIdx.x;
    const int w  = t >> 6;          // wave 0..3
    const int l  = t & 63;          // lane
    const int wr = w >> 1;          // wave row (2x2 wave grid)
    const int wc = w & 1;           // wave col
    const int lr = l & 15;          // fragment row/col within 16
    const int kg = l >> 4;          // k-group 0..3

    const int nbn  = N >> 7;
    const int brow = (blockIdx.x / nbn) << 7;
    const int bcol = (blockIdx.x % nbn) << 7;

    // staging coords: thread t covers LDS bytes t*16 of each 4KB chunk
    const int srow = t >> 2;        // 0..63 (chunk 1 adds 64)
    const int scol = (t & 3) << 3;  // 0,8,16,24

    const unsigned short* aS0 = A + (size_t)(brow + srow) * K + scol;
    const unsigned short* aS1 = aS0 + (size_t)64 * K;
    const unsigned short* bS0 = B + (size_t)(bcol + srow) * K + scol;
    const unsigned short* bS1 = bS0 + (size_t)64 * K;

    unsigned short* lA0 = sA + w * 512;            // wave-uniform LDS bases
    unsigned short* lA1 = sA + 2048 + w * 512;
    unsigned short* lB0 = sB + w * 512;
    unsigned short* lB1 = sB + 2048 + w * 512;

    f32x4 acc[4][4];
#pragma unroll
    for (int m = 0; m < 4; ++m)
#pragma unroll
        for (int n = 0; n < 4; ++n)
            acc[m][n] = f32x4{0.f, 0.f, 0.f, 0.f};

    for (int k0 = 0; k0 < K; k0 += 32) {
        GLD16(aS0 + k0, lA0);
        GLD16(aS1 + k0, lA1);
        GLD16(bS0 + k0, lB0);
        GLD16(bS1 + k0, lB1);
        __syncthreads();   // drains vmcnt before any wave reads LDS

        bfrag_t af[4], bf[4];
#pragma unroll
        for (int m = 0; m < 4; ++m)
            af[m] = *(const bfrag_t*)(sA + ((wr << 6) + (m << 4) + lr) * 32 + (kg << 3));
#pragma unroll
        for (int n = 0; n < 4; ++n)
            bf[n] = *(const bfrag_t*)(sB + ((wc << 6) + (n << 4) + lr) * 32 + (kg << 3));

#pragma unroll
        for (int m = 0; m < 4; ++m)
#pragma unroll
            for (int n = 0; n < 4; ++n)
                acc[m][n] = __builtin_amdgcn_mfma_f32_16x16x32_bf16(af[m], bf[n], acc[m][n], 0, 0, 0);
        __syncthreads();   // all reads done before next stage overwrites LDS
    }

    // C/D layout: col = lane&15, row = (lane>>4)*4 + reg  (m89/m91 verified)
#pragma unroll
    for (int m = 0; m < 4; ++m) {
        const int gr = brow + (wr << 6) + (m << 4) + (kg << 2);
#pragma unroll
        for (int n = 0; n < 4; ++n) {
            const int gc = bcol + (wc << 6) + (n << 4) + lr;
            const float bv = bias[gc];
#pragma unroll
            for (int j = 0; j < 4; ++j)
                C[(size_t)(gr + j) * N + gc] = acc[m][n][j] + bv;
        }
    }
    (void)M;
}

// ---------------------------------------------------------------------------
// Fallback (only if ws too small or dims don't tile): fp32 tiled GEMM with
// on-the-fly dequant. Correct for any shape; slow.
// ---------------------------------------------------------------------------
__global__ void gemm_fallback_kernel(const float* __restrict__ X, const float* __restrict__ W,
                                     const float* __restrict__ bias, float* __restrict__ C,
                                     int M, int N, int K) {
    __shared__ float sX[16][17];
    __shared__ float sW[16][17];
    const int tx = threadIdx.x & 15;
    const int ty = threadIdx.x >> 4;
    const int row = blockIdx.y * 16 + ty;
    const int colBase = blockIdx.x * 16;
    const int col = colBase + tx;
    float acc = 0.f;
    for (int k0 = 0; k0 < K; k0 += 16) {
        sX[ty][tx] = (row < M && k0 + tx < K) ? X[(size_t)row * K + k0 + tx] : 0.f;
        const int wrow = colBase + ty;
        sW[ty][tx] = (wrow < N && k0 + tx < K) ? dequant(W[(size_t)wrow * K + k0 + tx]) : 0.f;
        __syncthreads();
#pragma unroll
        for (int kk = 0; kk < 16; ++kk)
            acc += sX[ty][kk] * sW[tx][kk];
        __syncthreads();
    }
    if (row < M && col < N)
        C[(size_t)row * N + col] = acc + bias[col];
}

extern "C" void kernel_launch(void* const* d_in, const int* in_sizes, int n_in,
                              void* d_out, int out_size, void* d_ws, size_t ws_size,
                              hipStream_t stream) {
    const float* x    = (const float*)d_in[0];
    const float* w    = (const float*)d_in[1];
    const float* bias = (const float*)d_in[2];
    float* out        = (float*)d_out;

    const int N = in_sizes[2];
    const int K = in_sizes[1] / N;
    const int M = in_sizes[0] / K;

    const size_t need = ((size_t)M * K + (size_t)N * K) * sizeof(unsigned short);
    const bool fast = (ws_size >= need) && (M % 128 == 0) && (N % 128 == 0) && (K % 32 == 0) &&
                      ((K % 8) == 0);

    if (fast) {
        unsigned short* xb = (unsigned short*)d_ws;
        unsigned short* wb = xb + (size_t)M * K;
        const int n8x = (M / 8) * K / 1;  // M*K/8
        const int n8w = (N / 8) * K / 1;  // N*K/8
        cvtX_kernel<<<dim3(2048), dim3(256), 0, stream>>>(x, xb, (M * K) / 8);
        quantW_kernel<<<dim3(2048), dim3(256), 0, stream>>>(w, wb, (N * K) / 8);
        (void)n8x; (void)n8w;
        gemm_bt_kernel<<<dim3((M / 128) * (N / 128)), dim3(256), 0, stream>>>(xb, wb, bias, out, M, N, K);
    } else {
        dim3 g((N + 15) / 16, (M + 15) / 16);
        gemm_fallback_kernel<<<g, dim3(256), 0, stream>>>(x, w, bias, out, M, N, K);
    }
    (void)n_in; (void)out_size;
}

// Round 2
// 271.291 us; speedup vs baseline: 1.4468x; 1.4468x over previous
//
#include <hip/hip_runtime.h>
#include <stdint.h>

#define THRESH 0.5f
#define PSI 0.1f

typedef short bfrag_t __attribute__((ext_vector_type(8)));     // 8 bf16 = 4 VGPRs (MFMA A/B frag)
typedef float f32x4 __attribute__((ext_vector_type(4)));       // MFMA C/D frag
typedef unsigned short u16x8 __attribute__((ext_vector_type(8)));

// async global->LDS, 16B per lane, wave-uniform LDS base + lane*16
#define GLD16(gsrc, ldst)                                                                \
    __builtin_amdgcn_global_load_lds((const __attribute__((address_space(1))) void*)(gsrc), \
                                     (__attribute__((address_space(3))) void*)(ldst),       \
                                     16, 0, 0)

#define WAITVM(n) asm volatile("s_waitcnt vmcnt(" #n ")" ::: "memory")
#define BAR()                                  \
    do {                                       \
        asm volatile("" ::: "memory");         \
        __builtin_amdgcn_s_barrier();          \
        asm volatile("" ::: "memory");         \
    } while (0)

__device__ __forceinline__ float dequant(float v) {
    if (v > THRESH) return 1.0f;
    if (v < -THRESH) return -1.0f;
    if (fabsf(v) < PSI) return 0.0f;
    return (v + THRESH) / (2.0f * THRESH);
}

__device__ __forceinline__ unsigned short f2bf(float f) {
    unsigned int u = __float_as_uint(f);
    u += 0x7FFFu + ((u >> 16) & 1u);
    return (unsigned short)(u >> 16);
}

__global__ void quantW_kernel(const float* __restrict__ w, unsigned short* __restrict__ wb, int n8) {
    const int stride = gridDim.x * blockDim.x;
    for (int i = blockIdx.x * blockDim.x + threadIdx.x; i < n8; i += stride) {
        const float4* p = (const float4*)w + (size_t)i * 2;
        float4 a = p[0], b = p[1];
        u16x8 o;
        o[0] = f2bf(dequant(a.x)); o[1] = f2bf(dequant(a.y));
        o[2] = f2bf(dequant(a.z)); o[3] = f2bf(dequant(a.w));
        o[4] = f2bf(dequant(b.x)); o[5] = f2bf(dequant(b.y));
        o[6] = f2bf(dequant(b.z)); o[7] = f2bf(dequant(b.w));
        *(u16x8*)(wb + (size_t)i * 8) = o;
    }
}

__global__ void cvtX_kernel(const float* __restrict__ x, unsigned short* __restrict__ xb, int n8) {
    const int stride = gridDim.x * blockDim.x;
    for (int i = blockIdx.x * blockDim.x + threadIdx.x; i < n8; i += stride) {
        const float4* p = (const float4*)x + (size_t)i * 2;
        float4 a = p[0], b = p[1];
        u16x8 o;
        o[0] = f2bf(a.x); o[1] = f2bf(a.y); o[2] = f2bf(a.z); o[3] = f2bf(a.w);
        o[4] = f2bf(b.x); o[5] = f2bf(b.y); o[6] = f2bf(b.z); o[7] = f2bf(b.w);
        *(u16x8*)(xb + (size_t)i * 8) = o;
    }
}

// ---------------------------------------------------------------------------
// 256x256 8-phase bf16 GEMM: C[M,N] = A[M,K] * B[N,K]^T + bias, fp32 out.
// 8 waves (2Mx4N), BK=64 as two 32-k halves, 128 KiB LDS double-buffered,
// counted vmcnt(8) (never 0 in-loop), raw s_barrier, XOR-swizzled LDS,
// setprio around MFMA clusters, XCD-swizzled blockIdx.
// ---------------------------------------------------------------------------

// swizzle: involution on 16KB half-tile, flips 16B-granule bits 4-6 by row bits 1-3
__device__ __forceinline__ int swz(int b) { return b ^ (((b >> 7) & 7) << 4); }

__device__ __forceinline__ bfrag_t rdfrag(const char* halfBase, int row, int kg) {
    const int ll = (row << 6) | (kg << 4);   // logical byte in [256][32]-bf16 half-tile
    return *(const bfrag_t*)(halfBase + swz(ll));
}

__device__ __forceinline__ void mfma4x4(f32x4 (&acc)[8][4], int mbase, const bfrag_t* a, const bfrag_t* b) {
#pragma unroll
    for (int mm = 0; mm < 4; ++mm)
#pragma unroll
        for (int nn = 0; nn < 4; ++nn)
            acc[mbase + mm][nn] =
                __builtin_amdgcn_mfma_f32_16x16x32_bf16(a[mm], b[nn], acc[mbase + mm][nn], 0, 0, 0);
}

__global__ __launch_bounds__(512, 2) void gemm256_kernel(
        const unsigned short* __restrict__ A,   // M x K, bf16 bits
        const unsigned short* __restrict__ B,   // N x K, bf16 bits
        const float* __restrict__ bias,         // N
        float* __restrict__ C,                  // M x N
        int M, int N, int K) {
    __shared__ unsigned short lds[65536];       // 128 KiB: 2 bufs x {A0,A1,B0,B1} x 16 KiB
    char* ldsB = (char*)lds;

    const int t  = threadIdx.x;
    const int w  = t >> 6;          // wave 0..7
    const int l  = t & 63;
    const int wr = w >> 2;          // 0..1  (128-row band)
    const int wc = w & 3;           // 0..3  (64-col band)
    const int lr = l & 15;
    const int kg = l >> 4;

    // XCD-aware block swizzle (bijective when nwg % 8 == 0)
    const int nwg = gridDim.x;
    int bid = blockIdx.x;
    if ((nwg & 7) == 0) bid = (bid & 7) * (nwg >> 3) + (bid >> 3);
    const int nbn  = N >> 8;
    const int brow = (bid / nbn) << 8;
    const int bcol = (bid % nbn) << 8;

    // ---- staging precompute: thread covers 16B granules c = w*2+j of each half-tile
    const int b0 = ((w * 2 + 0) << 10) + (l << 4);
    const int b1 = ((w * 2 + 1) << 10) + (l << 4);
    const int l0 = swz(b0), l1 = swz(b1);
    const int row0 = l0 >> 6, col0 = (l0 & 63) >> 1;   // element coords in [256][32]
    const int row1 = l1 >> 6, col1 = (l1 & 63) >> 1;

    const unsigned short* aS0 = A + (size_t)(brow + row0) * K + col0;
    const unsigned short* aS1 = A + (size_t)(brow + row1) * K + col1;
    const unsigned short* bS0 = B + (size_t)(bcol + row0) * K + col0;
    const unsigned short* bS1 = B + (size_t)(bcol + row1) * K + col1;

    // LDS half-tile bases (bytes): buf*65536 + {A0:0, A1:16384, B0:32768, B1:49152}
#define STAGE_A(buf, half, kE)                                                              \
    do {                                                                                    \
        GLD16(aS0 + (kE) + (half) * 32, ldsB + (buf) * 65536 + (half) * 16384 + (w * 2 + 0) * 1024); \
        GLD16(aS1 + (kE) + (half) * 32, ldsB + (buf) * 65536 + (half) * 16384 + (w * 2 + 1) * 1024); \
    } while (0)
#define STAGE_B(buf, half, kE)                                                              \
    do {                                                                                    \
        GLD16(bS0 + (kE) + (half) * 32, ldsB + (buf) * 65536 + 32768 + (half) * 16384 + (w * 2 + 0) * 1024); \
        GLD16(bS1 + (kE) + (half) * 32, ldsB + (buf) * 65536 + 32768 + (half) * 16384 + (w * 2 + 1) * 1024); \
    } while (0)

    f32x4 acc[8][4];
#pragma unroll
    for (int m = 0; m < 8; ++m)
#pragma unroll
        for (int n = 0; n < 4; ++n)
            acc[m][n] = f32x4{0.f, 0.f, 0.f, 0.f};

    const int NT = K >> 6;
    const int wrBase = wr << 7;     // 0 / 128
    const int wcBase = wc << 6;     // 0 / 64 / 128 / 192

    // ---- prologue: buf0 fully (A0,B0,A1,B1), buf1 (A0,B0). 12 issues. ----
    {
        const int k1 = (NT > 1) ? 64 : 0;
        STAGE_A(0, 0, 0); STAGE_B(0, 0, 0);
        STAGE_A(0, 1, 0); STAGE_B(0, 1, 0);
        STAGE_A(1, 0, k1); STAGE_B(1, 0, k1);
        WAITVM(4);          // buf0 complete; buf1.A0/B0 (4 issues) stay in flight
        BAR();
    }

    for (int tt = 0; tt < NT; ++tt) {
        const int X = tt & 1, Y = X ^ 1;
        const char* aH0 = ldsB + X * 65536;
        const char* aH1 = aH0 + 16384;
        const char* bH0 = aH0 + 32768;
        const char* bH1 = aH0 + 49152;
        int t1 = tt + 1; if (t1 >= NT) t1 -= NT;   // wrapped: data harmless, never read
        int t2 = tt + 2; if (t2 >= NT) t2 -= NT;
        const int kY1 = t1 << 6;
        const int kX2 = t2 << 6;

        bfrag_t a[4], b[4];

        // ---- phase 1: A0 m0-3 + B0 all; stage Y.A1(t+1); MFMA kk0 m0-3 ----
#pragma unroll
        for (int mm = 0; mm < 4; ++mm) a[mm] = rdfrag(aH0, wrBase + mm * 16 + lr, kg);
#pragma unroll
        for (int nn = 0; nn < 4; ++nn) b[nn] = rdfrag(bH0, wcBase + nn * 16 + lr, kg);
        STAGE_A(Y, 1, kY1);
        BAR();
        __builtin_amdgcn_s_setprio(1);
        mfma4x4(acc, 0, a, b);
        __builtin_amdgcn_s_setprio(0);
        BAR();

        // ---- phase 2: A0 m4-7; stage Y.B1(t+1); MFMA kk0 m4-7 ----
#pragma unroll
        for (int mm = 0; mm < 4; ++mm) a[mm] = rdfrag(aH0, wrBase + 64 + mm * 16 + lr, kg);
        STAGE_B(Y, 1, kY1);
        BAR();
        __builtin_amdgcn_s_setprio(1);
        mfma4x4(acc, 4, a, b);
        __builtin_amdgcn_s_setprio(0);
        WAITVM(8);          // completes buf(t).A1/B1 for phase 3
        BAR();

        // ---- phase 3: A1 m0-3 + B1 all; stage X.A0(t+2); MFMA kk1 m0-3 ----
#pragma unroll
        for (int mm = 0; mm < 4; ++mm) a[mm] = rdfrag(aH1, wrBase + mm * 16 + lr, kg);
#pragma unroll
        for (int nn = 0; nn < 4; ++nn) b[nn] = rdfrag(bH1, wcBase + nn * 16 + lr, kg);
        STAGE_A(X, 0, kX2);                      // X.A0 free: last read was phase 2
        BAR();
        __builtin_amdgcn_s_setprio(1);
        mfma4x4(acc, 0, a, b);
        __builtin_amdgcn_s_setprio(0);
        BAR();

        // ---- phase 4: A1 m4-7; stage X.B0(t+2); MFMA kk1 m4-7 ----
#pragma unroll
        for (int mm = 0; mm < 4; ++mm) a[mm] = rdfrag(aH1, wrBase + 64 + mm * 16 + lr, kg);
        STAGE_B(X, 0, kX2);                      // X.B0 free: last read was phase 1
        BAR();
        __builtin_amdgcn_s_setprio(1);
        mfma4x4(acc, 4, a, b);
        __builtin_amdgcn_s_setprio(0);
        WAITVM(8);          // completes buf(t+1).A0/B0 for next tile's phase 1
        BAR();
    }

    WAITVM(0);              // drain pending LDS writes before wave retires

    // ---- epilogue: C/D layout col=lane&15, row=(lane>>4)*4+reg ----
    float bv[4];
#pragma unroll
    for (int nn = 0; nn < 4; ++nn) bv[nn] = bias[bcol + wcBase + nn * 16 + lr];
#pragma unroll
    for (int mm = 0; mm < 8; ++mm) {
        const int gr = brow + wrBase + mm * 16 + (kg << 2);
#pragma unroll
        for (int nn = 0; nn < 4; ++nn) {
            const int gc = bcol + wcBase + nn * 16 + lr;
#pragma unroll
            for (int j = 0; j < 4; ++j)
                C[(size_t)(gr + j) * N + gc] = acc[mm][nn][j] + bv[nn];
        }
    }
    (void)M;
#undef STAGE_A
#undef STAGE_B
}

// ---------------------------------------------------------------------------
// Fallback: fp32 tiled GEMM with on-the-fly dequant (any shape, slow).
// ---------------------------------------------------------------------------
__global__ void gemm_fallback_kernel(const float* __restrict__ X, const float* __restrict__ W,
                                     const float* __restrict__ bias, float* __restrict__ C,
                                     int M, int N, int K) {
    __shared__ float sX[16][17];
    __shared__ float sW[16][17];
    const int tx = threadIdx.x & 15;
    const int ty = threadIdx.x >> 4;
    const int row = blockIdx.y * 16 + ty;
    const int colBase = blockIdx.x * 16;
    const int col = colBase + tx;
    float acc = 0.f;
    for (int k0 = 0; k0 < K; k0 += 16) {
        sX[ty][tx] = (row < M && k0 + tx < K) ? X[(size_t)row * K + k0 + tx] : 0.f;
        const int wrow = colBase + ty;
        sW[ty][tx] = (wrow < N && k0 + tx < K) ? dequant(W[(size_t)wrow * K + k0 + tx]) : 0.f;
        __syncthreads();
#pragma unroll
        for (int kk = 0; kk < 16; ++kk)
            acc += sX[ty][kk] * sW[tx][kk];
        __syncthreads();
    }
    if (row < M && col < N)
        C[(size_t)row * N + col] = acc + bias[col];
}

extern "C" void kernel_launch(void* const* d_in, const int* in_sizes, int n_in,
                              void* d_out, int out_size, void* d_ws, size_t ws_size,
                              hipStream_t stream) {
    const float* x    = (const float*)d_in[0];
    const float* w    = (const float*)d_in[1];
    const float* bias = (const float*)d_in[2];
    float* out        = (float*)d_out;

    const int N = in_sizes[2];
    const int K = in_sizes[1] / N;
    const int M = in_sizes[0] / K;

    const size_t need = ((size_t)M * K + (size_t)N * K) * sizeof(unsigned short);
    const bool fast = (ws_size >= need) && (M % 256 == 0) && (N % 256 == 0) && (K % 64 == 0) && (K >= 128);

    if (fast) {
        unsigned short* xb = (unsigned short*)d_ws;
        unsigned short* wb = xb + (size_t)M * K;
        cvtX_kernel<<<dim3(2048), dim3(256), 0, stream>>>(x, xb, (M * K) / 8);
        quantW_kernel<<<dim3(2048), dim3(256), 0, stream>>>(w, wb, (N * K) / 8);
        gemm256_kernel<<<dim3((M / 256) * (N / 256)), dim3(512), 0, stream>>>(xb, wb, bias, out, M, N, K);
    } else {
        dim3 g((N + 15) / 16, (M + 15) / 16);
        gemm_fallback_kernel<<<g, dim3(256), 0, stream>>>(x, w, bias, out, M, N, K);
    }
    (void)n_in; (void)out_size;
}